// Round 10
// baseline (620.645 us; speedup 1.0000x reference)
//
#include <hip/hip_runtime.h>
#include <hip/hip_bf16.h>

constexpr int N = 10000;   // nodes
constexpr int D = 512;     // feature dim
constexpr int E = 160000;  // edges
constexpr int L = 3;       // layers
constexpr float EPS = 1e-5f;

typedef _Float16 half8 __attribute__((ext_vector_type(8)));
typedef _Float16 half2v __attribute__((ext_vector_type(2)));
typedef float floatx4 __attribute__((ext_vector_type(4)));

// async global->LDS, 16B per lane. LDS dest = wave-uniform base + lane*16.
__device__ __forceinline__ void glds16(const _Float16* g, _Float16* l) {
    __builtin_amdgcn_global_load_lds(
        (const __attribute__((address_space(1))) uint32_t*)(g),
        (__attribute__((address_space(3))) uint32_t*)(l),
        16, 0, 0);
}

// ---------------------------------------------------------------------------
// Mega setup: degrees + x fp32->f16 + column stats + W transpose. (r7 verbatim)
// ---------------------------------------------------------------------------
constexpr int DEG_BLOCKS  = (E + 255) / 256;   // 625
constexpr int CONV_BLOCKS = 100;
constexpr int TW_BLOCKS   = L * 256;           // 768
constexpr int MEGA_BLOCKS = DEG_BLOCKS + CONV_BLOCKS + TW_BLOCKS;

__global__ __launch_bounds__(256) void mega_setup(
    const int* __restrict__ src, const int* __restrict__ dst,
    const float* __restrict__ x, const float* __restrict__ W,
    int* __restrict__ out_deg, int* __restrict__ in_deg,
    _Float16* __restrict__ x16, float* __restrict__ stats0,
    _Float16* __restrict__ Wt) {
    __shared__ float tb[32][33];
    int bid = blockIdx.x;
    int tid = threadIdx.x;
    if (bid < DEG_BLOCKS) {
        int e = bid * 256 + tid;
        if (e < E) {
            atomicAdd(&out_deg[src[e]], 1);
            atomicAdd(&in_deg[dst[e]], 1);
        }
    } else if (bid < DEG_BLOCKS + CONV_BLOCKS) {
        int b = bid - DEG_BLOCKS;
        int r0 = b * 100;
        int r1 = r0 + 100; if (r1 > N) r1 = N;
        int c2 = tid * 2;
        float s0 = 0.f, s1 = 0.f, q0 = 0.f, q1 = 0.f;
        for (int r = r0; r < r1; ++r) {
            float2 v = *(const float2*)(x + (size_t)r * D + c2);
            s0 += v.x; q0 += v.x * v.x;
            s1 += v.y; q1 += v.y * v.y;
            half2v h; h[0] = (_Float16)v.x; h[1] = (_Float16)v.y;
            *(half2v*)(x16 + (size_t)r * D + c2) = h;
        }
        atomicAdd(&stats0[c2], s0);
        atomicAdd(&stats0[c2 + 1], s1);
        atomicAdd(&stats0[D + c2], q0);
        atomicAdd(&stats0[D + c2 + 1], q1);
    } else {
        int b = bid - DEG_BLOCKS - CONV_BLOCKS;
        int l = b >> 8;
        int t = b & 255;
        int k0 = (t >> 4) * 32, n0 = (t & 15) * 32;
        int tx = tid & 31, ty = tid >> 5;
        const float* Wl = W + (size_t)l * D * D;
        _Float16* Wtl = Wt + (size_t)l * D * D;
        for (int i = 0; i < 32; i += 8)
            tb[ty + i][tx] = Wl[(size_t)(k0 + ty + i) * D + n0 + tx];
        __syncthreads();
        for (int i = 0; i < 32; i += 8)
            Wtl[(size_t)(n0 + ty + i) * D + k0 + tx] = (_Float16)tb[tx][ty + i];
    }
}

// ---------------------------------------------------------------------------
// Merged scan + csr_fill. Block 0 scans (256 threads); blocks 1..625 spin on
// flag then fill. All 626 blocks co-resident (tiny VGPR) -> deadlock-free.
// ---------------------------------------------------------------------------
__global__ __launch_bounds__(256) void scan_fill(
    const int* __restrict__ in_deg, const int* __restrict__ out_deg,
    int* __restrict__ off, int* __restrict__ cursor,
    float* __restrict__ src_norm, float* __restrict__ dst_norm,
    const int* __restrict__ src, const int* __restrict__ dst,
    int* __restrict__ csr_src, int* flag) {
    if (blockIdx.x == 0) {
        __shared__ int lsum[256];
        int t = threadIdx.x;
        const int chunk = (N + 255) / 256;  // 40
        int start = t * chunk;
        int end = start + chunk; if (end > N) end = N;
        int s = 0;
        for (int i = start; i < end; ++i) s += in_deg[i];
        lsum[t] = s;
        __syncthreads();
        for (int d = 1; d < 256; d <<= 1) {
            int v = (t >= d) ? lsum[t - d] : 0;
            __syncthreads();
            lsum[t] += v;
            __syncthreads();
        }
        int excl = (t == 0) ? 0 : lsum[t - 1];
        for (int i = start; i < end; ++i) {
            off[i] = excl;
            cursor[i] = excl;
            excl += in_deg[i];
            int od = out_deg[i]; if (od < 1) od = 1;
            int id = in_deg[i];  if (id < 1) id = 1;
            src_norm[i] = rsqrtf((float)od);
            dst_norm[i] = rsqrtf((float)id);
        }
        if (t == 255) off[N] = lsum[255];
        __syncthreads();
        if (t == 0)
            __hip_atomic_store(flag, 1, __ATOMIC_RELEASE, __HIP_MEMORY_SCOPE_AGENT);
    } else {
        if (threadIdx.x == 0) {
            while (!__hip_atomic_load(flag, __ATOMIC_RELAXED, __HIP_MEMORY_SCOPE_AGENT))
                __builtin_amdgcn_s_sleep(8);
            (void)__hip_atomic_load(flag, __ATOMIC_ACQUIRE, __HIP_MEMORY_SCOPE_AGENT);
        }
        __syncthreads();
        __builtin_amdgcn_fence(__ATOMIC_ACQUIRE, "agent");
        int e = (blockIdx.x - 1) * 256 + threadIdx.x;
        if (e < E) {
            int d_ = dst[e];
            int pos = atomicAdd(&cursor[d_], 1);
            csr_src[pos] = src[e];
        }
    }
}

// ---------------------------------------------------------------------------
// Merged per-layer kernel: 2500 agg blocks + 316 mm blocks in one grid.
// agg block b: nodes 4b..4b+3 (wave-per-node gather, BN folded), then
// release-increment rb_cnt[b>>5]. mm block (rb,cb): spin until its 128-row
// strip's producers done (32, or 4 for the last strip), acquire, then the r7
// 128x128 glds16-staged MFMA mm + bias + relu + stats epilogue.
// Deadlock-safe by capacity: <=316 spinners < resident-block capacity.
// ---------------------------------------------------------------------------
constexpr int AGG_BLOCKS = N / 4;          // 2500
constexpr int MM_RB = (N + 127) / 128;     // 79
constexpr int MM_CB = D / 128;             // 4
constexpr int MM_BLOCKS = MM_RB * MM_CB;   // 316

template <typename OutT, bool STATS>
__global__ __launch_bounds__(256) void layer_merged(
    const _Float16* __restrict__ xin, const int* __restrict__ off,
    const int* __restrict__ csr_src, const float* __restrict__ src_norm,
    const float* __restrict__ dst_norm, const float* __restrict__ stats_in,
    const float* __restrict__ gamma, const float* __restrict__ beta,
    _Float16* __restrict__ agg, const _Float16* __restrict__ Bt,
    const float* __restrict__ bias, OutT* __restrict__ C,
    float* __restrict__ stats_out, int* __restrict__ rb_cnt) {
    __shared__ __align__(16) _Float16 As[128 * 32];
    __shared__ __align__(16) _Float16 Bs[128 * 32];
    const int tid  = threadIdx.x;
    const int bid  = blockIdx.x;
    const int wave = tid >> 6;
    const int lane = tid & 63;
    const int quad = lane >> 4;
    const int l16  = lane & 15;

    if (bid < AGG_BLOCKS) {
        // ---- gather path (r7 verbatim) ----
        int n = bid * 4 + wave;
        int c0 = lane * 8;
        float scale[8], shift[8];
        const float invN = 1.0f / (float)N;
        for (int i = 0; i < 8; ++i) {
            int c = c0 + i;
            float mu = stats_in[c] * invN;
            float var = stats_in[D + c] * invN - mu * mu;
            float sc = gamma[c] * rsqrtf(var + EPS);
            scale[i] = sc;
            shift[i] = beta[c] - mu * sc;
        }
        int e0 = off[n], e1 = off[n + 1];
        float a[8] = {}, a2[8] = {};
        float t = 0.f;
        int e = e0;
        for (; e + 4 <= e1; e += 4) {
            int s0 = csr_src[e];
            int s1 = csr_src[e + 1];
            int s2 = csr_src[e + 2];
            int s3 = csr_src[e + 3];
            float n0 = src_norm[s0];
            float n1 = src_norm[s1];
            float n2 = src_norm[s2];
            float n3 = src_norm[s3];
            half8 v0 = *(const half8*)(xin + (size_t)s0 * D + c0);
            half8 v1 = *(const half8*)(xin + (size_t)s1 * D + c0);
            half8 v2 = *(const half8*)(xin + (size_t)s2 * D + c0);
            half8 v3 = *(const half8*)(xin + (size_t)s3 * D + c0);
            t += (n0 + n1) + (n2 + n3);
            for (int k = 0; k < 8; ++k) {
                a[k]  += (float)v0[k] * n0;
                a2[k] += (float)v1[k] * n1;
                a[k]  += (float)v2[k] * n2;
                a2[k] += (float)v3[k] * n3;
            }
        }
        for (; e < e1; ++e) {
            int s0 = csr_src[e];
            float n0 = src_norm[s0];
            half8 v0 = *(const half8*)(xin + (size_t)s0 * D + c0);
            t += n0;
            for (int k = 0; k < 8; ++k) a[k] += (float)v0[k] * n0;
        }
        float dn = dst_norm[n];
        half8 o;
        for (int i = 0; i < 8; ++i)
            o[i] = (_Float16)(dn * (scale[i] * (a[i] + a2[i]) + shift[i] * t));
        *(half8*)(agg + (size_t)n * D + c0) = o;
        __syncthreads();  // drains all waves' stores (vmcnt(0) before barrier)
        if (tid == 0)
            __hip_atomic_fetch_add(&rb_cnt[bid >> 5], 1, __ATOMIC_RELEASE,
                                   __HIP_MEMORY_SCOPE_AGENT);
        return;
    }

    // ---- mm path ----
    const int idx = bid - AGG_BLOCKS;
    const int rb = idx % MM_RB;
    const int cb = idx / MM_RB;
    if (tid == 0) {
        const int target = (rb < N / 128) ? 32 : (N / 4 - (N / 128) * 32);  // 32 or 4
        while (__hip_atomic_load(&rb_cnt[rb], __ATOMIC_RELAXED,
                                 __HIP_MEMORY_SCOPE_AGENT) < target)
            __builtin_amdgcn_s_sleep(8);
        (void)__hip_atomic_load(&rb_cnt[rb], __ATOMIC_ACQUIRE,
                                __HIP_MEMORY_SCOPE_AGENT);
    }
    __syncthreads();
    __builtin_amdgcn_fence(__ATOMIC_ACQUIRE, "agent");

    const int row0 = rb * 128;
    const int col0 = cb * 128;
    const int wm = (wave & 1) * 64;
    const int wn = (wave >> 1) * 64;
    const int sr = lane >> 2;
    const int sc = (lane & 3) * 8;

    int ar0 = row0 + wave * 32 + sr;
    int ar1 = ar0 + 16;
    if (ar0 >= N) ar0 = N - 1;
    if (ar1 >= N) ar1 = N - 1;
    const _Float16* gA0 = agg + (size_t)ar0 * D + sc;
    const _Float16* gA1 = agg + (size_t)ar1 * D + sc;
    const _Float16* gB0 = Bt + (size_t)(col0 + wave * 32 + sr) * D + sc;
    const _Float16* gB1 = Bt + (size_t)(col0 + wave * 32 + 16 + sr) * D + sc;
    _Float16* lA0 = As + (wave * 32) * 32;
    _Float16* lA1 = As + (wave * 32 + 16) * 32;
    _Float16* lB0 = Bs + (wave * 32) * 32;
    _Float16* lB1 = Bs + (wave * 32 + 16) * 32;

    floatx4 acc[4][4] = {};

    for (int k0 = 0; k0 < D; k0 += 32) {
        __syncthreads();
        glds16(gA0 + k0, lA0);
        glds16(gA1 + k0, lA1);
        glds16(gB0 + k0, lB0);
        glds16(gB1 + k0, lB1);
        __syncthreads();
        half8 af[4], bf[4];
        for (int i = 0; i < 4; ++i)
            af[i] = *(const half8*)(As + (wm + i * 16 + l16) * 32 + quad * 8);
        for (int j = 0; j < 4; ++j)
            bf[j] = *(const half8*)(Bs + (wn + j * 16 + l16) * 32 + quad * 8);
        for (int i = 0; i < 4; ++i)
            for (int j = 0; j < 4; ++j)
                acc[i][j] = __builtin_amdgcn_mfma_f32_16x16x32_f16(
                    af[i], bf[j], acc[i][j], 0, 0, 0);
    }

    // epilogue: C/D layout col = lane&15, row = quad*4 + reg
    float s[4] = {}, q[4] = {};
    for (int i = 0; i < 4; ++i) {
        for (int r = 0; r < 4; ++r) {
            int row = row0 + wm + i * 16 + quad * 4 + r;
            bool valid = row < N;
            for (int j = 0; j < 4; ++j) {
                int col = col0 + wn + j * 16 + l16;
                float v = acc[i][j][r] + bias[col];
                v = v > 0.f ? v : 0.f;
                if (valid) {
                    C[(size_t)row * D + col] = (OutT)v;
                    if (STATS) { s[j] += v; q[j] += v * v; }
                }
            }
        }
    }
    if (STATS) {
        for (int j = 0; j < 4; ++j) {
            float sv = s[j], qv = q[j];
            sv += __shfl_xor(sv, 16); sv += __shfl_xor(sv, 32);
            qv += __shfl_xor(qv, 16); qv += __shfl_xor(qv, 32);
            if (quad == 0) {
                int col = col0 + wn + j * 16 + l16;
                atomicAdd(&stats_out[col], sv);
                atomicAdd(&stats_out[D + col], qv);
            }
        }
    }
}

// ---------------------------------------------------------------------------
extern "C" void kernel_launch(void* const* d_in, const int* in_sizes, int n_in,
                              void* d_out, int out_size, void* d_ws, size_t ws_size,
                              hipStream_t stream) {
    const float* x_in  = (const float*)d_in[0];
    const int*   src   = (const int*)d_in[1];
    const int*   dst   = (const int*)d_in[2];
    const float* gamma = (const float*)d_in[3];
    const float* beta  = (const float*)d_in[4];
    const float* W     = (const float*)d_in[5];
    const float* b     = (const float*)d_in[6];
    float* out = (float*)d_out;

    // workspace carve-up (16B-aligned segments first)
    char* p = (char*)d_ws;
    _Float16* x16a = (_Float16*)p; p += (size_t)N * D * 2;   // layer inputs ping
    _Float16* x16b = (_Float16*)p; p += (size_t)N * D * 2;   // layer inputs pong
    _Float16* agg  = (_Float16*)p; p += (size_t)N * D * 2;   // aggregation buffer
    _Float16* Wt   = (_Float16*)p; p += (size_t)L * D * D * 2;
    float* src_norm = (float*)p;   p += (size_t)N * 4;
    float* dst_norm = (float*)p;   p += (size_t)N * 4;
    // contiguous zero-init region: out_deg, in_deg, stats0..2, flag, rb_cnt
    int* out_deg   = (int*)p;      p += (size_t)N * 4;
    int* in_deg    = (int*)p;      p += (size_t)N * 4;
    float* stats0  = (float*)p;    p += 2 * D * 4;
    float* stats1  = (float*)p;    p += 2 * D * 4;
    float* stats2  = (float*)p;    p += 2 * D * 4;
    int* flag      = (int*)p;      p += 16 * 4;
    int* rb_cnt    = (int*)p;      p += 3 * 128 * 4;   // 79 used per layer
    size_t zero_bytes = (size_t)((char*)p - (char*)out_deg);
    int* csr_off   = (int*)p;      p += (size_t)(N + 1) * 4;
    int* cursor    = (int*)p;      p += (size_t)N * 4;
    int* csr_src   = (int*)p;      p += (size_t)E * 4;

    // --- setup: 3 dispatches + memset ---
    hipMemsetAsync(out_deg, 0, zero_bytes, stream);
    mega_setup<<<MEGA_BLOCKS, 256, 0, stream>>>(src, dst, x_in, W,
                                                out_deg, in_deg, x16a, stats0, Wt);
    scan_fill<<<1 + DEG_BLOCKS, 256, 0, stream>>>(in_deg, out_deg, csr_off, cursor,
                                                  src_norm, dst_norm, src, dst,
                                                  csr_src, flag);

    const int grid = AGG_BLOCKS + MM_BLOCKS;  // 2816

    // layer 0: x16a -> x16b
    layer_merged<_Float16, true><<<grid, 256, 0, stream>>>(
        x16a, csr_off, csr_src, src_norm, dst_norm, stats0, gamma, beta,
        agg, Wt, b, x16b, stats1, rb_cnt);
    // layer 1: x16b -> x16a
    layer_merged<_Float16, true><<<grid, 256, 0, stream>>>(
        x16b, csr_off, csr_src, src_norm, dst_norm, stats1, gamma + D, beta + D,
        agg, Wt + (size_t)D * D, b + D, x16a, stats2, rb_cnt + 128);
    // layer 2: x16a -> out (fp32)
    layer_merged<float, false><<<grid, 256, 0, stream>>>(
        x16a, csr_off, csr_src, src_norm, dst_norm, stats2, gamma + 2 * D, beta + 2 * D,
        agg, Wt + 2 * (size_t)D * D, b + 2 * D, out, nullptr, rb_cnt + 256);
}

// Round 11
// 303.614 us; speedup vs baseline: 2.0442x; 2.0442x over previous
//
#include <hip/hip_runtime.h>
#include <hip/hip_bf16.h>

constexpr int N = 10000;   // nodes
constexpr int D = 512;     // feature dim
constexpr int E = 160000;  // edges
constexpr int L = 3;       // layers
constexpr float EPS = 1e-5f;
constexpr int CHUNK = 128; // feature columns per chunk
constexpr int NCH = D / CHUNK;  // 4

typedef _Float16 half8 __attribute__((ext_vector_type(8)));
typedef _Float16 half4v __attribute__((ext_vector_type(4)));
typedef _Float16 half2v __attribute__((ext_vector_type(2)));
typedef float floatx4 __attribute__((ext_vector_type(4)));

// async global->LDS, 16B per lane. LDS dest = wave-uniform base + lane*16.
__device__ __forceinline__ void glds16(const _Float16* g, _Float16* l) {
    __builtin_amdgcn_global_load_lds(
        (const __attribute__((address_space(1))) uint32_t*)(g),
        (__attribute__((address_space(3))) uint32_t*)(l),
        16, 0, 0);
}

// ---------------------------------------------------------------------------
// Mega setup: degrees + x fp32->f16 (chunked [4][N][128]) + col stats + W^T.
// ---------------------------------------------------------------------------
constexpr int DEG_BLOCKS  = (E + 255) / 256;   // 625
constexpr int CONV_BLOCKS = 100;               // 100 rows each
constexpr int TW_BLOCKS   = L * 256;           // 768 (32x32 tiles)
constexpr int MEGA_BLOCKS = DEG_BLOCKS + CONV_BLOCKS + TW_BLOCKS;

__global__ __launch_bounds__(256) void mega_setup(
    const int* __restrict__ src, const int* __restrict__ dst,
    const float* __restrict__ x, const float* __restrict__ W,
    int* __restrict__ out_deg, int* __restrict__ in_deg,
    _Float16* __restrict__ x16, float* __restrict__ stats0,
    _Float16* __restrict__ Wt) {
    __shared__ float tb[32][33];
    int bid = blockIdx.x;
    int tid = threadIdx.x;
    if (bid < DEG_BLOCKS) {
        int e = bid * 256 + tid;
        if (e < E) {
            atomicAdd(&out_deg[src[e]], 1);
            atomicAdd(&in_deg[dst[e]], 1);
        }
    } else if (bid < DEG_BLOCKS + CONV_BLOCKS) {
        int b = bid - DEG_BLOCKS;
        int r0 = b * 100;
        int r1 = r0 + 100; if (r1 > N) r1 = N;
        int c2 = tid * 2;                 // global col pair
        int ch = c2 >> 7;                 // chunk
        int lc = c2 & 127;                // local col
        _Float16* xc = x16 + (size_t)ch * N * CHUNK;
        float s0 = 0.f, s1 = 0.f, q0 = 0.f, q1 = 0.f;
        for (int r = r0; r < r1; ++r) {
            float2 v = *(const float2*)(x + (size_t)r * D + c2);
            s0 += v.x; q0 += v.x * v.x;
            s1 += v.y; q1 += v.y * v.y;
            half2v h; h[0] = (_Float16)v.x; h[1] = (_Float16)v.y;
            *(half2v*)(xc + (size_t)r * CHUNK + lc) = h;
        }
        atomicAdd(&stats0[c2], s0);
        atomicAdd(&stats0[c2 + 1], s1);
        atomicAdd(&stats0[D + c2], q0);
        atomicAdd(&stats0[D + c2 + 1], q1);
    } else {
        int b = bid - DEG_BLOCKS - CONV_BLOCKS;  // 0..767
        int l = b >> 8;
        int t = b & 255;
        int k0 = (t >> 4) * 32, n0 = (t & 15) * 32;
        int tx = tid & 31, ty = tid >> 5;  // 32 x 8
        const float* Wl = W + (size_t)l * D * D;
        _Float16* Wtl = Wt + (size_t)l * D * D;
        for (int i = 0; i < 32; i += 8)
            tb[ty + i][tx] = Wl[(size_t)(k0 + ty + i) * D + n0 + tx];
        __syncthreads();
        for (int i = 0; i < 32; i += 8)
            Wtl[(size_t)(n0 + ty + i) * D + k0 + tx] = (_Float16)tb[tx][ty + i];
    }
}

// ---------------------------------------------------------------------------
// Single block: exclusive scan of in_deg -> off & cursor, plus both norms.
// ---------------------------------------------------------------------------
__global__ void scan_indeg(const int* __restrict__ in_deg,
                           const int* __restrict__ out_deg,
                           int* __restrict__ off, int* __restrict__ cursor,
                           float* __restrict__ src_norm, float* __restrict__ dst_norm) {
    __shared__ int lsum[1024];
    int t = threadIdx.x;
    const int chunk = (N + 1023) / 1024;
    int start = t * chunk;
    int end = start + chunk; if (end > N) end = N;
    int s = 0;
    for (int i = start; i < end; ++i) s += in_deg[i];
    lsum[t] = s;
    __syncthreads();
    for (int d = 1; d < 1024; d <<= 1) {
        int v = (t >= d) ? lsum[t - d] : 0;
        __syncthreads();
        lsum[t] += v;
        __syncthreads();
    }
    int excl = (t == 0) ? 0 : lsum[t - 1];
    for (int i = start; i < end; ++i) {
        off[i] = excl;
        cursor[i] = excl;
        excl += in_deg[i];
        int od = out_deg[i]; if (od < 1) od = 1;
        int id = in_deg[i];  if (id < 1) id = 1;
        src_norm[i] = rsqrtf((float)od);
        dst_norm[i] = rsqrtf((float)id);
    }
    if (t == 1023) off[N] = lsum[1023];
}

__global__ void csr_fill(const int* __restrict__ src, const int* __restrict__ dst,
                         int* __restrict__ cursor, int* __restrict__ csr_src) {
    int e = blockIdx.x * blockDim.x + threadIdx.x;
    if (e >= E) return;
    int d = dst[e];
    int pos = atomicAdd(&cursor[d], 1);
    csr_src[pos] = src[e];
}

// ---------------------------------------------------------------------------
// Fused BN + gather-aggregate, chunked + XCD-pinned, 2 edges per wave-inst.
// Grid: (N/8)*8 blocks. bid = g*8 + xx; chunk = xx>>1 (pinned: bid%8 -> XCD,
// so each chunk's 2.5 MB stays resident in 2 XCDs' L2); sub = xx&1;
// wave w handles node g*8 + sub*4 + w.
// Within a wave: lanes 0-31 gather even edges, lanes 32-63 odd edges,
// 4 cols (8B dwordx2) per lane -> 512B per VMEM inst, halves combined by
// shfl_xor(32). Edge indices stay wave-uniform scalar loads.
// ---------------------------------------------------------------------------
__global__ __launch_bounds__(256) void aggregate_bn(
    const _Float16* __restrict__ x, const int* __restrict__ off,
    const int* __restrict__ csr_src, const float* __restrict__ src_norm,
    const float* __restrict__ dst_norm, const float* __restrict__ stats,
    const float* __restrict__ gamma, const float* __restrict__ beta,
    _Float16* __restrict__ agg) {
    int bid = blockIdx.x;
    int g = bid >> 3;
    int xx = bid & 7;
    int ch = xx >> 1;
    int sub = xx & 1;
    int wave = threadIdx.x >> 6;
    int lane = threadIdx.x & 63;
    int half = lane >> 5;            // edge parity handled by this lane
    int l32 = lane & 31;
    int n = g * 8 + sub * 4 + wave;  // N divisible by 8 -> always valid
    int lc = l32 * 4;                // local col in chunk (4 f16 per lane)
    int gc = ch * CHUNK + lc;        // global col

    const _Float16* xc = x + (size_t)ch * N * CHUNK;
    _Float16* ac = agg + (size_t)ch * N * CHUNK;

    float scale[4], shift[4];
    const float invN = 1.0f / (float)N;
    for (int i = 0; i < 4; ++i) {
        int c = gc + i;
        float mu = stats[c] * invN;
        float var = stats[D + c] * invN - mu * mu;
        float sc = gamma[c] * rsqrtf(var + EPS);
        scale[i] = sc;
        shift[i] = beta[c] - mu * sc;
    }

    int e0 = off[n], e1 = off[n + 1];
    float a[4] = {}, a2[4] = {};
    float t = 0.f;
    int e = e0;
    for (; e + 4 <= e1; e += 4) {
        int s0 = csr_src[e];
        int s1 = csr_src[e + 1];
        int s2 = csr_src[e + 2];
        int s3 = csr_src[e + 3];
        float n0 = src_norm[s0];
        float n1 = src_norm[s1];
        float n2 = src_norm[s2];
        float n3 = src_norm[s3];
        int sa = half ? s1 : s0;
        int sb = half ? s3 : s2;
        float na = half ? n1 : n0;
        float nb = half ? n3 : n2;
        half4v va = *(const half4v*)(xc + (size_t)sa * CHUNK + lc);
        half4v vb = *(const half4v*)(xc + (size_t)sb * CHUNK + lc);
        t += na + nb;
        for (int k = 0; k < 4; ++k) {
            a[k]  += (float)va[k] * na;
            a2[k] += (float)vb[k] * nb;
        }
    }
    int rem = e1 - e;  // 0..3
    if (half < rem) {                 // edge e+half
        int sa = csr_src[e + half];
        float na = src_norm[sa];
        half4v va = *(const half4v*)(xc + (size_t)sa * CHUNK + lc);
        t += na;
        for (int k = 0; k < 4; ++k) a[k] += (float)va[k] * na;
    }
    if (half + 2 < rem) {             // edge e+2 (rem==3, half==0 only)
        int sa = csr_src[e + half + 2];
        float na = src_norm[sa];
        half4v va = *(const half4v*)(xc + (size_t)sa * CHUNK + lc);
        t += na;
        for (int k = 0; k < 4; ++k) a[k] += (float)va[k] * na;
    }

    // combine even/odd halves
    t += __shfl_xor(t, 32);
    float dn = dst_norm[n];
    half4v o;
    for (int k = 0; k < 4; ++k) {
        float af = a[k] + a2[k];
        af += __shfl_xor(af, 32);
        o[k] = (_Float16)(dn * (scale[k] * af + shift[k] * t));
    }
    if (half == 0)
        *(half4v*)(ac + (size_t)n * CHUNK + lc) = o;
}

// ---------------------------------------------------------------------------
// C = relu(A @ W + bias) via f16 MFMA with global_load_lds staging.
// A: chunked [NCH][M][CHUNK] f16.  Bt[n][k] = W[k][n], row-major 512.
// Block 256 = 4 waves; tile 128(M) x 128(N); BK=32.
// STATS=true: output written chunked f16 + next-layer stats.
// STATS=false: output row-major (OutT).
// ---------------------------------------------------------------------------
template <typename OutT, bool STATS>
__global__ __launch_bounds__(256) void mm_f16_relu(
    const _Float16* __restrict__ A, const _Float16* __restrict__ Bt,
    const float* __restrict__ bias, OutT* __restrict__ C, int M,
    float* __restrict__ stats) {
    __shared__ __align__(16) _Float16 As[128 * 32];
    __shared__ __align__(16) _Float16 Bs[128 * 32];
    const int tid  = threadIdx.x;
    const int wave = tid >> 6;
    const int lane = tid & 63;
    const int quad = lane >> 4;
    const int l16  = lane & 15;
    const int row0 = blockIdx.x * 128;
    const int col0 = blockIdx.y * 128;
    const int wm = (wave & 1) * 64;
    const int wn = (wave >> 1) * 64;
    const int sr = lane >> 2;
    const int sc = (lane & 3) * 8;

    int ar0 = row0 + wave * 32 + sr;
    int ar1 = ar0 + 16;
    if (ar0 >= M) ar0 = M - 1;
    if (ar1 >= M) ar1 = M - 1;
    const size_t aoff0 = (size_t)ar0 * CHUNK + sc;
    const size_t aoff1 = (size_t)ar1 * CHUNK + sc;
    const _Float16* gB0 = Bt + (size_t)(col0 + wave * 32 + sr) * D + sc;
    const _Float16* gB1 = Bt + (size_t)(col0 + wave * 32 + 16 + sr) * D + sc;
    _Float16* lA0 = As + (wave * 32) * 32;
    _Float16* lA1 = As + (wave * 32 + 16) * 32;
    _Float16* lB0 = Bs + (wave * 32) * 32;
    _Float16* lB1 = Bs + (wave * 32 + 16) * 32;

    floatx4 acc[4][4] = {};

    for (int k0 = 0; k0 < D; k0 += 32) {
        const _Float16* Ac = A + (size_t)(k0 >> 7) * M * CHUNK + (k0 & 127);
        __syncthreads();
        glds16(Ac + aoff0, lA0);
        glds16(Ac + aoff1, lA1);
        glds16(gB0 + k0, lB0);
        glds16(gB1 + k0, lB1);
        __syncthreads();  // compiler inserts vmcnt(0) drain here
        half8 af[4], bf[4];
        for (int i = 0; i < 4; ++i)
            af[i] = *(const half8*)(As + (wm + i * 16 + l16) * 32 + quad * 8);
        for (int j = 0; j < 4; ++j)
            bf[j] = *(const half8*)(Bs + (wn + j * 16 + l16) * 32 + quad * 8);
        for (int i = 0; i < 4; ++i)
            for (int j = 0; j < 4; ++j)
                acc[i][j] = __builtin_amdgcn_mfma_f32_16x16x32_f16(
                    af[i], bf[j], acc[i][j], 0, 0, 0);
    }

    // epilogue: C/D layout col = lane&15, row = quad*4 + reg
    // STATS path writes chunked f16: chunk = col0>>7 (constant per block).
    _Float16* Cc = (_Float16*)C + (size_t)(col0 >> 7) * M * CHUNK;
    float s[4] = {}, q[4] = {};
    for (int i = 0; i < 4; ++i) {
        for (int r = 0; r < 4; ++r) {
            int row = row0 + wm + i * 16 + quad * 4 + r;
            bool valid = row < M;
            for (int j = 0; j < 4; ++j) {
                int lcol = wn + j * 16 + l16;       // local col in 128-chunk
                float v = acc[i][j][r] + bias[col0 + lcol];
                v = v > 0.f ? v : 0.f;
                if (valid) {
                    if (STATS) {
                        Cc[(size_t)row * CHUNK + lcol] = (_Float16)v;
                        s[j] += v; q[j] += v * v;
                    } else {
                        C[(size_t)row * D + col0 + lcol] = (OutT)v;
                    }
                }
            }
        }
    }
    if (STATS) {
        for (int j = 0; j < 4; ++j) {
            float sv = s[j], qv = q[j];
            sv += __shfl_xor(sv, 16); sv += __shfl_xor(sv, 32);
            qv += __shfl_xor(qv, 16); qv += __shfl_xor(qv, 32);
            if (quad == 0) {
                int col = col0 + wn + j * 16 + l16;
                atomicAdd(&stats[col], sv);
                atomicAdd(&stats[D + col], qv);
            }
        }
    }
}

// ---------------------------------------------------------------------------
extern "C" void kernel_launch(void* const* d_in, const int* in_sizes, int n_in,
                              void* d_out, int out_size, void* d_ws, size_t ws_size,
                              hipStream_t stream) {
    const float* x_in  = (const float*)d_in[0];
    const int*   src   = (const int*)d_in[1];
    const int*   dst   = (const int*)d_in[2];
    const float* gamma = (const float*)d_in[3];
    const float* beta  = (const float*)d_in[4];
    const float* W     = (const float*)d_in[5];
    const float* b     = (const float*)d_in[6];
    float* out = (float*)d_out;

    // workspace carve-up (16B-aligned segments first)
    char* p = (char*)d_ws;
    _Float16* x16 = (_Float16*)p;  p += (size_t)N * D * 2;       // chunked [4][N][128]
    _Float16* agg = (_Float16*)p;  p += (size_t)N * D * 2;       // chunked [4][N][128]
    _Float16* Wt  = (_Float16*)p;  p += (size_t)L * D * D * 2;   // 1.57 MB
    float* src_norm = (float*)p;   p += (size_t)N * 4;
    float* dst_norm = (float*)p;   p += (size_t)N * 4;
    // contiguous zero-init region: out_deg, in_deg, stats0..2
    int* out_deg   = (int*)p;      p += (size_t)N * 4;
    int* in_deg    = (int*)p;      p += (size_t)N * 4;
    float* stats0  = (float*)p;    p += 2 * D * 4;
    float* stats1  = (float*)p;    p += 2 * D * 4;
    float* stats2  = (float*)p;    p += 2 * D * 4;
    int* csr_off   = (int*)p;      p += (size_t)(N + 1) * 4;
    int* cursor    = (int*)p;      p += (size_t)N * 4;
    int* csr_src   = (int*)p;      p += (size_t)E * 4;

    float* stats_in[3] = {stats0, stats1, stats2};

    // --- setup ---
    hipMemsetAsync(out_deg, 0, (2 * (size_t)N + 6 * D) * sizeof(int), stream);
    mega_setup<<<MEGA_BLOCKS, 256, 0, stream>>>(src, dst, x_in, W,
                                                out_deg, in_deg, x16, stats0, Wt);
    scan_indeg<<<1, 1024, 0, stream>>>(in_deg, out_deg, csr_off, cursor,
                                       src_norm, dst_norm);
    csr_fill<<<DEG_BLOCKS, 256, 0, stream>>>(src, dst, cursor, csr_src);

    dim3 mm_grid((N + 127) / 128, D / 128);
    const int agg_blocks = (N / 8) * 8;  // 10000: (node-group, chunk, sub)

    for (int l = 0; l < L; ++l) {
        const float* gl  = gamma + (size_t)l * D;
        const float* bl  = beta + (size_t)l * D;
        const _Float16* Wl = Wt + (size_t)l * D * D;
        const float* bil = b + (size_t)l * D;

        aggregate_bn<<<agg_blocks, 256, 0, stream>>>(
            x16, csr_off, csr_src, src_norm, dst_norm, stats_in[l], gl, bl, agg);
        if (l == L - 1) {
            mm_f16_relu<float, false><<<mm_grid, 256, 0, stream>>>(
                agg, Wl, bil, out, N, nullptr);
        } else {
            mm_f16_relu<_Float16, true><<<mm_grid, 256, 0, stream>>>(
                agg, Wl, bil, x16, N, stats_in[l + 1]);
        }
    }
}